// Round 5
// baseline (295.941 us; speedup 1.0000x reference)
//
#include <hip/hip_runtime.h>
#include <hip/hip_bf16.h>

#define DEPTH 25
#define DIM   64
#define HID   100

typedef _Float16 f16x4 __attribute__((ext_vector_type(4)));
typedef _Float16 f16x2 __attribute__((ext_vector_type(2)));
typedef float    f32x4 __attribute__((ext_vector_type(4)));
typedef float    f32x2 __attribute__((ext_vector_type(2)));

// packed f32->f16 (RTZ) returning _Float16x2
static __device__ __forceinline__ f16x2 cvt_pk(float a, float b) {
    return __builtin_bit_cast(f16x2, __builtin_amdgcn_cvt_pkrtz(a, b));
}

// ---- module-global scratch (NOT d_ws: ws_size is unknown; R4's 38KB ws
// usage overran it and corrupted harness buffers). Rewritten every call. ----
__device__ __align__(16) float    g_noise[DEPTH * DIM];
__device__ __align__(16) float    g_b1p[112];
__device__ __align__(16) float    g_W2p[112];
__device__ __align__(16) _Float16 g_frWdown [64 * 64];
__device__ __align__(16) _Float16 g_frWdrift[64 * 64];   // dt-scaled
__device__ __align__(16) _Float16 g_frW1    [64 * 112];  // zero-padded

// ---- Pre-kernel: Levy noise + per-lane MFMA fragment packing ----
// Fragment contents depend only on lane id, NOT on block — compute once.
__global__ __launch_bounds__(256) void prep_kernel(
    const float* __restrict__ u_raw, const float* __restrict__ w_raw,
    const float* __restrict__ W_down, const float* __restrict__ W_drift,
    const float* __restrict__ W1,     const float* __restrict__ b1,
    const float* __restrict__ W2)
{
    const int tid = threadIdx.x;

    for (int idx = tid; idx < DEPTH * DIM; idx += 256) {
        float u = u_raw[idx];
        float w = w_raw[idx];
        float U  = 3.14159265358979323846f * (u - 0.5f);
        float Wv = -logf(fminf(fmaxf(w, 1e-12f), 1.0f));
        float t1 = sinf(1.8f * U) / powf(cosf(U), 0.5555555555555556f);
        float ratio = cosf(0.8f * U) / fmaxf(Wv, 1e-12f);
        float X = t1 * powf(ratio, -0.4444444444444444f);
        g_noise[idx] = fminf(fmaxf(0.1f * X, -10.0f), 10.0f);
    }
    if (tid < 112) {
        g_b1p[tid] = (tid < HID) ? b1[tid] : 0.0f;
        g_W2p[tid] = (tid < HID) ? W2[tid] : 0.0f;
    }
    if (tid < 64) {
        const int l = tid, r = l & 15, g = l >> 4;
        for (int Mt = 0; Mt < 4; ++Mt)
            for (int kt = 0; kt < 4; ++kt)
                for (int i = 0; i < 4; ++i) {
                    int k = kt * 16 + g * 4 + i, col = Mt * 16 + r;
                    g_frWdown [l * 64 + Mt * 16 + kt * 4 + i] = (_Float16)W_down[k * DIM + col];
                    g_frWdrift[l * 64 + Mt * 16 + kt * 4 + i] = (_Float16)(0.04f * W_drift[k * DIM + col]);
                }
        for (int Mt = 0; Mt < 7; ++Mt) {
            int ncol = Mt * 16 + r;
            for (int kt = 0; kt < 4; ++kt)
                for (int i = 0; i < 4; ++i) {
                    int k = kt * 16 + g * 4 + i;
                    g_frW1[l * 112 + Mt * 16 + kt * 4 + i] =
                        (ncol < HID) ? (_Float16)W1[k * HID + ncol] : (_Float16)0.0f;
                }
        }
    }
}

// ---- Main kernel: 256 threads = 4 waves; each wave owns 32 batch rows
// (two independent 16-row groups -> two parallel MFMA dependency chains).
// State kept transposed; 16x16x16f16 C/D layout == B-operand layout, so the
// accumulator feeds the next step's B fragment with only a packed f32->f16
// convert (v_cvt_pkrtz). dt folded into W_drift/b_drift.
__global__ __launch_bounds__(256) void sdenet_fused(
    const float* __restrict__ x,
    const float* __restrict__ b_down, const float* __restrict__ b_drift,
    const float* __restrict__ b2, float* __restrict__ out, int batch)
{
    __shared__ float noise_lds[DEPTH * DIM];

    const int tid = threadIdx.x;
    {
        const float4* src = (const float4*)g_noise;
        float4* dst = (float4*)noise_lds;
        for (int idx = tid; idx < DEPTH * DIM / 4; idx += 256)
            dst[idx] = src[idx];
    }
    __syncthreads();

    const int wave = tid >> 6;
    const int lane = tid & 63;
    const int r    = lane & 15;
    const int g    = lane >> 4;
    const int row0 = blockIdx.x * 128 + wave * 32 + r;   // group 0
    const int row1 = row0 + 16;                           // group 1

    // ---- initial GEMM: out0^T = W_down^T @ x^T + b_down, both groups ----
    f16x4 bfrag[2][4];
    #pragma unroll
    for (int kt = 0; kt < 4; ++kt) {
        const float4 xv0 = *(const float4*)(x + (long long)row0 * DIM + kt * 16 + g * 4);
        const float4 xv1 = *(const float4*)(x + (long long)row1 * DIM + kt * 16 + g * 4);
        f16x2 a0 = cvt_pk(xv0.x, xv0.y), a1 = cvt_pk(xv0.z, xv0.w);
        f16x2 b0 = cvt_pk(xv1.x, xv1.y), b1v = cvt_pk(xv1.z, xv1.w);
        bfrag[0][kt] = (f16x4){a0[0], a0[1], a1[0], a1[1]};
        bfrag[1][kt] = (f16x4){b0[0], b0[1], b1v[0], b1v[1]};
    }

    f32x2 st[2][4][2];    // master fp32 state, C/D layout, per group
    #pragma unroll
    for (int Mt = 0; Mt < 4; ++Mt) {
        const f32x4 bdn = *(const f32x4*)(b_down + Mt * 16 + g * 4);
        #pragma unroll
        for (int gr = 0; gr < 2; ++gr) {
            f32x4 acc = bdn;
            #pragma unroll
            for (int kt = 0; kt < 4; ++kt) {
                const f16x4 a = *(const f16x4*)(g_frWdown + lane * 64 + Mt * 16 + kt * 4);
                acc = __builtin_amdgcn_mfma_f32_16x16x16f16(a, bfrag[gr][kt], acc, 0, 0, 0);
            }
            st[gr][Mt][0] = (f32x2){acc[0], acc[1]};
            st[gr][Mt][1] = (f32x2){acc[2], acc[3]};
        }
    }
    #pragma unroll
    for (int gr = 0; gr < 2; ++gr)
        #pragma unroll
        for (int kt = 0; kt < 4; ++kt) {
            f16x2 lo = cvt_pk(st[gr][kt][0][0], st[gr][kt][0][1]);
            f16x2 hi = cvt_pk(st[gr][kt][1][0], st[gr][kt][1][1]);
            bfrag[gr][kt] = (f16x4){lo[0], lo[1], hi[0], hi[1]};
        }

    // ---- head on initial state: logit = relu(out0@W1+b1p)@W2p + b2 ----
    float partial[2] = {0.0f, 0.0f};
    #pragma unroll
    for (int Mt = 0; Mt < 7; ++Mt) {
        const f32x4 binit = *(const f32x4*)(g_b1p + Mt * 16 + g * 4);
        const f32x4 w2v   = *(const f32x4*)(g_W2p + Mt * 16 + g * 4);
        #pragma unroll
        for (int gr = 0; gr < 2; ++gr) {
            f32x4 acc = binit;
            #pragma unroll
            for (int kt = 0; kt < 4; ++kt) {
                const f16x4 a = *(const f16x4*)(g_frW1 + lane * 112 + Mt * 16 + kt * 4);
                acc = __builtin_amdgcn_mfma_f32_16x16x16f16(a, bfrag[gr][kt], acc, 0, 0, 0);
            }
            #pragma unroll
            for (int reg = 0; reg < 4; ++reg)
                partial[gr] += fmaxf(acc[reg], 0.0f) * w2v[reg];
        }
    }
    f32x2 scl[2];
    #pragma unroll
    for (int gr = 0; gr < 2; ++gr) {
        float p = partial[gr];
        p += __shfl_xor(p, 16);
        p += __shfl_xor(p, 32);
        const float logit = p + b2[0];
        const float s = 0.5f * (1.0f / (1.0f + expf(-logit)))
                      * powf(0.04f, 1.0f / 1.8f);
        scl[gr] = (f32x2){s, s};
    }

    // ---- persistent dt-scaled W_drift^T fragments + dt*b_drift ----
    f16x4 aWd[4][4];
    #pragma unroll
    for (int Mt = 0; Mt < 4; ++Mt)
        #pragma unroll
        for (int kt = 0; kt < 4; ++kt)
            aWd[Mt][kt] = *(const f16x4*)(g_frWdrift + lane * 64 + Mt * 16 + kt * 4);
    f32x4 biasd[4];
    #pragma unroll
    for (int Mt = 0; Mt < 4; ++Mt) {
        f32x4 b = *(const f32x4*)(b_drift + Mt * 16 + g * 4);
        biasd[Mt] = (f32x4){b[0] * 0.04f, b[1] * 0.04f, b[2] * 0.04f, b[3] * 0.04f};
    }

    const f32x2 c104 = {1.04f, 1.04f};
    const f32x2 zero2 = {0.0f, 0.0f};

    // ---- 25 SDE steps, all in registers ----
    for (int t = 0; t < DEPTH; ++t) {
        f32x4 nz[4];
        #pragma unroll
        for (int Mt = 0; Mt < 4; ++Mt)
            nz[Mt] = *(const f32x4*)(noise_lds + t * DIM + Mt * 16 + g * 4);

        f32x4 acc[2][4];
        #pragma unroll
        for (int gr = 0; gr < 2; ++gr)
            #pragma unroll
            for (int Mt = 0; Mt < 4; ++Mt) {
                acc[gr][Mt] = biasd[Mt];
                #pragma unroll
                for (int kt = 0; kt < 4; ++kt)
                    acc[gr][Mt] = __builtin_amdgcn_mfma_f32_16x16x16f16(
                        aWd[Mt][kt], bfrag[gr][kt], acc[gr][Mt], 0, 0, 0);
            }
        #pragma unroll
        for (int gr = 0; gr < 2; ++gr) {
            #pragma unroll
            for (int Mt = 0; Mt < 4; ++Mt) {
                #pragma unroll
                for (int h = 0; h < 2; ++h) {
                    f32x2 a2 = {acc[gr][Mt][2 * h], acc[gr][Mt][2 * h + 1]};
                    f32x2 n2 = {nz[Mt][2 * h], nz[Mt][2 * h + 1]};
                    f32x2 rel = __builtin_elementwise_max(a2, zero2);
                    f32x2 tmp = __builtin_elementwise_fma(st[gr][Mt][h], c104, rel);
                    st[gr][Mt][h] = __builtin_elementwise_fma(scl[gr], n2, tmp);
                }
            }
            #pragma unroll
            for (int kt = 0; kt < 4; ++kt) {
                f16x2 lo = cvt_pk(st[gr][kt][0][0], st[gr][kt][0][1]);
                f16x2 hi = cvt_pk(st[gr][kt][1][0], st[gr][kt][1][1]);
                bfrag[gr][kt] = (f16x4){lo[0], lo[1], hi[0], hi[1]};
            }
        }
    }

    // ---- final drift (undo dt scaling: relu(z) = relu(dt*z)*25) + stores ----
    const long long out2_off = (long long)batch * DIM;
    #pragma unroll
    for (int gr = 0; gr < 2; ++gr) {
        const long long rowg = (gr == 0) ? row0 : row1;
        #pragma unroll
        for (int Mt = 0; Mt < 4; ++Mt) {
            f32x4 acc = biasd[Mt];
            #pragma unroll
            for (int kt = 0; kt < 4; ++kt)
                acc = __builtin_amdgcn_mfma_f32_16x16x16f16(aWd[Mt][kt], bfrag[gr][kt], acc, 0, 0, 0);
            float o0 = st[gr][Mt][0][0], o1 = st[gr][Mt][0][1];
            float o2 = st[gr][Mt][1][0], o3 = st[gr][Mt][1][1];
            float4 dv, ov;
            dv.x = fmaf(fmaxf(acc[0], 0.0f), 25.0f, o0);
            dv.y = fmaf(fmaxf(acc[1], 0.0f), 25.0f, o1);
            dv.z = fmaf(fmaxf(acc[2], 0.0f), 25.0f, o2);
            dv.w = fmaf(fmaxf(acc[3], 0.0f), 25.0f, o3);
            ov.x = o0; ov.y = o1; ov.z = o2; ov.w = o3;
            *(float4*)(out + rowg * DIM + Mt * 16 + g * 4) = dv;
            *(float4*)(out + out2_off + rowg * DIM + Mt * 16 + g * 4) = ov;
        }
    }
}

extern "C" void kernel_launch(void* const* d_in, const int* in_sizes, int n_in,
                              void* d_out, int out_size, void* d_ws, size_t ws_size,
                              hipStream_t stream) {
    const float* x       = (const float*)d_in[0];
    const float* u_raw   = (const float*)d_in[1];
    const float* w_raw   = (const float*)d_in[2];
    const float* W_down  = (const float*)d_in[3];
    const float* b_down  = (const float*)d_in[4];
    const float* W_drift = (const float*)d_in[5];
    const float* b_drift = (const float*)d_in[6];
    const float* W1      = (const float*)d_in[7];
    const float* b1      = (const float*)d_in[8];
    const float* W2      = (const float*)d_in[9];
    const float* b2      = (const float*)d_in[10];
    float* out = (float*)d_out;

    const int batch = in_sizes[0] / DIM;       // 262144
    const int blocks = batch / 128;            // 32 rows/wave * 4 waves

    prep_kernel<<<1, 256, 0, stream>>>(u_raw, w_raw, W_down, W_drift, W1, b1, W2);
    sdenet_fused<<<blocks, 256, 0, stream>>>(x, b_down, b_drift, b2, out, batch);
}